// Round 1
// baseline (510.140 us; speedup 1.0000x reference)
//
#include <hip/hip_runtime.h>
#include <hip/hip_bf16.h>

#define T_ 256
#define B_ 16
#define S_ 64
#define D_ 256

typedef __attribute__((ext_vector_type(8))) short short8;
typedef __attribute__((ext_vector_type(4))) float floatx4;

__device__ __forceinline__ short f2bf(float f) {
    union { float f; unsigned u; } uf; uf.f = f;
    unsigned r = uf.u + 0x7FFFu + ((uf.u >> 16) & 1u);  // RNE to bf16
    return (short)(r >> 16);
}

__device__ __forceinline__ float tanh_fast(float x) {
    // tanh(x) = 1 - 2/(1+exp(2x)); handles +-inf saturation correctly
    float e = __expf(2.0f * x);
    float r = __builtin_amdgcn_rcpf(e + 1.0f);
    return __builtin_fmaf(-2.0f, r, 1.0f);
}

// ---------------- W_x transpose: WxT[k][d] = W_x[d][k] ----------------
__global__ void k_transpose(const float* __restrict__ in, float* __restrict__ out) {
    __shared__ float tile[32][33];
    int tx = threadIdx.x & 31, ty = threadIdx.x >> 5;
    int bx = blockIdx.x & 7, by = blockIdx.x >> 3;
    tile[ty][tx] = in[(by * 32 + ty) * D_ + bx * 32 + tx];
    __syncthreads();
    out[(bx * 32 + ty) * D_ + by * 32 + tx] = tile[tx][ty];
}

// -------- Wxall[t*B+b][d] = bias[d] + sum_k x[t,b,k] * WxT[k][d] --------
__global__ __launch_bounds__(256) void k_wxall(const float* __restrict__ x,
                                               const float* __restrict__ WxT,
                                               const float* __restrict__ bias,
                                               float* __restrict__ wxall) {
    __shared__ float xs[16][D_];
    const int tid = threadIdx.x;
    const int row0 = blockIdx.x * 16;
    for (int r = 0; r < 16; ++r)
        xs[r][tid] = x[(size_t)(row0 + r) * D_ + tid];
    __syncthreads();
    float acc[16];
    float bv = bias[tid];
#pragma unroll
    for (int r = 0; r < 16; ++r) acc[r] = bv;
    for (int k = 0; k < D_; ++k) {
        float wv = WxT[k * D_ + tid];           // coalesced
#pragma unroll
        for (int r = 0; r < 16; ++r) acc[r] = __builtin_fmaf(wv, xs[r][k], acc[r]);
    }
    for (int r = 0; r < 16; ++r)
        wxall[(size_t)(row0 + r) * D_ + tid] = acc[r];
}

// ---------------- h[0] = h0 ----------------
__global__ void k_h0copy(const float4* __restrict__ in, float4* __restrict__ out) {
    int i = blockIdx.x * blockDim.x + threadIdx.x;
    out[i] = in[i];
}

// ---------------- main recurrence ----------------
// grid = 256 blocks: block -> (b = blk>>4, slots s0..s0+3 with s0 = (blk&15)*4)
// block = 256 threads = 4 waves; wave w owns output d-slice [64w, 64w+64)
__global__ __launch_bounds__(256, 1) void k_rec(
    const float* __restrict__ Wh,      // [D][D]  (= W_h, normalization is a no-op)
    const float* __restrict__ wxall,   // [T*B][D], bias folded in
    const float* __restrict__ z,       // [T*B][D]
    const float* __restrict__ h0,      // [B][S][D]
    const float* __restrict__ Cvec,    // [S]
    float* __restrict__ outputs,       // [T*B][D], pre-zeroed (atomic accum)
    float* __restrict__ h_out)         // [(T+1)*B][S][D]
{
    const int tid  = threadIdx.x;
    const int w    = tid >> 6;
    const int lane = tid & 63;
    const int l16  = lane & 15;
    const int quad = lane >> 4;
    const int b    = blockIdx.x >> 4;
    const int s0   = (blockIdx.x & 15) * 4;

    // ping-pong h buffer, bf16. stride 272 shorts = 544B: 16B-aligned rows and
    // the (row=l16&3, quad) b128 read pattern maps exactly 2-way per bank (free).
    __shared__ __align__(16) short hA[2][4][272];

    // init hA[0] from h0
    for (int r = 0; r < 4; ++r) {
        float v = h0[(size_t)(b * S_ + s0 + r) * D_ + tid];
        hA[0][r][tid] = f2bf(v);
    }

    // Wh B-fragments in registers: B[k][n] = Wh[n_global][k_global]
    // lane holds B[k = kt*32 + quad*8 + j][n = 64w + nt*16 + l16]
    short8 Bf[8][4];
#pragma unroll
    for (int nt = 0; nt < 4; ++nt) {
        const float* wr = Wh + (size_t)(w * 64 + nt * 16 + l16) * D_ + quad * 8;
#pragma unroll
        for (int kt = 0; kt < 8; ++kt) {
            const float* p = wr + kt * 32;
            float4 lo = *(const float4*)(p);
            float4 hi = *(const float4*)(p + 4);
            short8 v;
            v[0] = f2bf(lo.x); v[1] = f2bf(lo.y); v[2] = f2bf(lo.z); v[3] = f2bf(lo.w);
            v[4] = f2bf(hi.x); v[5] = f2bf(hi.y); v[6] = f2bf(hi.z); v[7] = f2bf(hi.w);
            Bf[kt][nt] = v;
        }
    }

    const float Cc0 = Cvec[s0 + 0], Cc1 = Cvec[s0 + 1], Cc2 = Cvec[s0 + 2], Cc3 = Cvec[s0 + 3];
    const int dglob = w * 64 + lane;   // this lane's d in the epilogue
    __syncthreads();

    for (int t = 0; t < T_; ++t) {
        const int cur = t & 1, nxt = cur ^ 1;
        const int rowtb = t * B_ + b;
        float wx = wxall[(size_t)rowtb * D_ + dglob];   // independent of hA: overlaps MFMA
        float zv = z[(size_t)rowtb * D_ + dglob];

        floatx4 acc0 = {0.f, 0.f, 0.f, 0.f}, acc1 = acc0, acc2 = acc0, acc3 = acc0;
#pragma unroll
        for (int kt = 0; kt < 8; ++kt) {
            // A[m][k] = h_prev[slot m&3][k]; rows m>=4 broadcast rows 0-3 (no extra LDS BW)
            short8 Af = *(const short8*)&hA[cur][l16 & 3][kt * 32 + quad * 8];
            acc0 = __builtin_amdgcn_mfma_f32_16x16x32_bf16(Af, Bf[kt][0], acc0, 0, 0, 0);
            acc1 = __builtin_amdgcn_mfma_f32_16x16x32_bf16(Af, Bf[kt][1], acc1, 0, 0, 0);
            acc2 = __builtin_amdgcn_mfma_f32_16x16x32_bf16(Af, Bf[kt][2], acc2, 0, 0, 0);
            acc3 = __builtin_amdgcn_mfma_f32_16x16x32_bf16(Af, Bf[kt][3], acc3, 0, 0, 0);
        }

        float sig  = __builtin_amdgcn_rcpf(1.0f + __expf(-zv));
        float silu = zv * sig;
        float osum = 0.0f;
        size_t hbase = ((size_t)(t + 1) * B_ + b) * (S_ * D_) + (size_t)s0 * D_ + dglob;
#pragma unroll
        for (int r = 0; r < 4; ++r) {
            // valid C values (m=r<4) live in quad0 lanes: C[m=r][n=l16] at lane l16.
            // redistribute so lane l holds d = 64w + l  (nt = l>>4, n = l&15)
            float t0 = __shfl(acc0[r], l16, 64);
            float t1 = __shfl(acc1[r], l16, 64);
            float t2 = __shfl(acc2[r], l16, 64);
            float t3 = __shfl(acc3[r], l16, 64);
            float a01 = (quad & 1) ? t1 : t0;
            float a23 = (quad & 1) ? t3 : t2;
            float v   = (quad & 2) ? a23 : a01;
            float pre = v + wx;
            float hv  = tanh_fast(pre);
            h_out[hbase + (size_t)r * D_] = hv;          // coalesced 256B/wave
            hA[nxt][r][dglob] = f2bf(hv);                // next step's A operand
            float cr = (r == 0) ? Cc0 : (r == 1) ? Cc1 : (r == 2) ? Cc2 : Cc3;
            osum = __builtin_fmaf(cr, hv, osum);
        }
        // fold the s-reduction in here: 16 blocks contribute per (t,b,d)
        atomicAdd(&outputs[(size_t)rowtb * D_ + dglob], osum * silu);
        __syncthreads();   // ping-pong: single barrier per step
    }
}

extern "C" void kernel_launch(void* const* d_in, const int* in_sizes, int n_in,
                              void* d_out, int out_size, void* d_ws, size_t ws_size,
                              hipStream_t stream) {
    const float* x    = (const float*)d_in[0];
    const float* z    = (const float*)d_in[1];
    const float* h0   = (const float*)d_in[2];
    const float* W_x  = (const float*)d_in[3];
    const float* W_h  = (const float*)d_in[4];
    const float* bias = (const float*)d_in[5];
    const float* C    = (const float*)d_in[6];

    float* outputs = (float*)d_out;                     // [T*B*D]
    float* h_out   = outputs + (size_t)T_ * B_ * D_;    // [(T+1)*B*S*D]

    float* WxT   = (float*)d_ws;                        // D*D floats
    float* wxall = WxT + D_ * D_;                       // T*B*D floats

    hipMemsetAsync(outputs, 0, (size_t)T_ * B_ * D_ * sizeof(float), stream);
    k_transpose<<<64, 1024, 0, stream>>>(W_x, WxT);
    k_wxall<<<T_ * B_ / 16, 256, 0, stream>>>(x, WxT, bias, wxall);
    k_h0copy<<<(B_ * S_ * D_ / 4) / 256, 256, 0, stream>>>((const float4*)h0, (float4*)h_out);
    k_rec<<<B_ * S_ / 4, 256, 0, stream>>>(W_h, wxall, z, h0, C, outputs, h_out);
}

// Round 2
// 477.418 us; speedup vs baseline: 1.0685x; 1.0685x over previous
//
#include <hip/hip_runtime.h>
#include <hip/hip_bf16.h>

#define T_ 256
#define B_ 16
#define S_ 64
#define D_ 256

typedef __attribute__((ext_vector_type(8))) short short8;
typedef __attribute__((ext_vector_type(4))) float floatx4;

__device__ __forceinline__ short f2bf(float f) {
    union { float f; unsigned u; } uf; uf.f = f;
    unsigned r = uf.u + 0x7FFFu + ((uf.u >> 16) & 1u);  // RNE to bf16
    return (short)(r >> 16);
}

__device__ __forceinline__ float tanh_fast(float x) {
    // tanh(x) = 1 - 2/(1+exp(2x)); saturates correctly at +-inf
    float e = __expf(2.0f * x);
    float r = __builtin_amdgcn_rcpf(e + 1.0f);
    return __builtin_fmaf(-2.0f, r, 1.0f);
}

// ---------------- W_x transpose: WxT[k][d] = W_x[d][k] ----------------
__global__ void k_transpose(const float* __restrict__ in, float* __restrict__ out) {
    __shared__ float tile[32][33];
    int tx = threadIdx.x & 31, ty = threadIdx.x >> 5;
    int bx = blockIdx.x & 7, by = blockIdx.x >> 3;
    tile[ty][tx] = in[(by * 32 + ty) * D_ + bx * 32 + tx];
    __syncthreads();
    out[(bx * 32 + ty) * D_ + by * 32 + tx] = tile[tx][ty];
}

// -------- Wxall[t*B+b][d] = bias[d] + sum_k x[t,b,k] * WxT[k][d] --------
__global__ __launch_bounds__(256) void k_wxall(const float* __restrict__ x,
                                               const float* __restrict__ WxT,
                                               const float* __restrict__ bias,
                                               float* __restrict__ wxall) {
    __shared__ float xs[16][D_];
    const int tid = threadIdx.x;
    const int row0 = blockIdx.x * 16;
    for (int r = 0; r < 16; ++r)
        xs[r][tid] = x[(size_t)(row0 + r) * D_ + tid];
    __syncthreads();
    float acc[16];
    float bv = bias[tid];
#pragma unroll
    for (int r = 0; r < 16; ++r) acc[r] = bv;
    for (int k = 0; k < D_; ++k) {
        float wv = WxT[k * D_ + tid];           // coalesced
#pragma unroll
        for (int r = 0; r < 16; ++r) acc[r] = __builtin_fmaf(wv, xs[r][k], acc[r]);
    }
    for (int r = 0; r < 16; ++r)
        wxall[(size_t)(row0 + r) * D_ + tid] = acc[r];
}

// ---------------- main recurrence ----------------
// grid = 256 blocks: block -> (b = blk>>4, slots s0..s0+3, s0 = (blk&15)*4)
// block = 256 threads = 4 waves; wave w owns output d-slice [64w, 64w+64)
__global__ __launch_bounds__(256, 1) void k_rec(
    const float* __restrict__ Wh,      // [D][D]
    const float* __restrict__ wxall,   // [T*B][D], bias folded in
    const float* __restrict__ z,       // [T*B][D]
    const float* __restrict__ h0,      // [B][S][D]
    const float* __restrict__ Cvec,    // [S]
    float* __restrict__ outputs,       // [T*B][D], pre-zeroed (atomic accum)
    float* __restrict__ h_out)         // [(T+1)*B][S][D]
{
    const int tid  = threadIdx.x;
    const int w    = tid >> 6;
    const int lane = tid & 63;
    const int l16  = lane & 15;
    const int quad = lane >> 4;
    const int b    = blockIdx.x >> 4;
    const int s0   = (blockIdx.x & 15) * 4;

    // ping-pong h buffer, bf16. row stride 272 shorts (544 B): 16B-aligned rows;
    // the (row=l16&3, quad) b128 read pattern maps exactly 2-way per bank (free).
    __shared__ __align__(16) short hA[2][4][272];

    // init hA[0] from h0, and write h[0] = h0 (fold the old copy kernel in)
    for (int r = 0; r < 4; ++r) {
        float v = h0[(size_t)(b * S_ + s0 + r) * D_ + tid];
        hA[0][r][tid] = f2bf(v);
        h_out[(size_t)(b * S_ + s0 + r) * D_ + tid] = v;
    }

    // Wh B-fragments in registers: B[k][n] = Wh[n_global][k_global]
    // lane holds B[k = kt*32 + quad*8 + j][n = 64w + nt*16 + l16]
    short8 Bf[8][4];
#pragma unroll
    for (int nt = 0; nt < 4; ++nt) {
        const float* wr = Wh + (size_t)(w * 64 + nt * 16 + l16) * D_ + quad * 8;
#pragma unroll
        for (int kt = 0; kt < 8; ++kt) {
            const float* p = wr + kt * 32;
            float4 lo = *(const float4*)(p);
            float4 hi = *(const float4*)(p + 4);
            short8 v;
            v[0] = f2bf(lo.x); v[1] = f2bf(lo.y); v[2] = f2bf(lo.z); v[3] = f2bf(lo.w);
            v[4] = f2bf(hi.x); v[5] = f2bf(hi.y); v[6] = f2bf(hi.z); v[7] = f2bf(hi.w);
            Bf[kt][nt] = v;
        }
    }

    const float Cc0 = Cvec[s0 + 0], Cc1 = Cvec[s0 + 1], Cc2 = Cvec[s0 + 2], Cc3 = Cvec[s0 + 3];
    const int dglob = w * 64 + lane;
    __syncthreads();

    // prefetched wx/z for the CURRENT step
    float wx = wxall[(size_t)b * D_ + dglob];   // row t=0 is 0*B_+b
    float zv = z[(size_t)b * D_ + dglob];

    // 2-deep deferred global stores (indexed by t&1); flushed at t+2 so the
    // pre-barrier vmcnt(0) drain never waits on a fresh HBM store/atomic.
    float  dh[2][4];
    float  dos[2];
    size_t dhb[2];
    size_t dob[2];

    for (int t = 0; t < T_; ++t) {
        const int cur = t & 1, nxt = cur ^ 1, par = t & 1;

        // issue A-fragment LDS reads first (latency head start)
        short8 Af[8];
#pragma unroll
        for (int kt = 0; kt < 8; ++kt)
            Af[kt] = *(const short8*)&hA[cur][l16 & 3][kt * 32 + quad * 8];

        // flush step t-2's global traffic (overlaps this step's MFMA phase)
        if (t >= 2) {
            float* hp = h_out + dhb[par];
            __builtin_nontemporal_store(dh[par][0], hp);
            __builtin_nontemporal_store(dh[par][1], hp + D_);
            __builtin_nontemporal_store(dh[par][2], hp + 2 * D_);
            __builtin_nontemporal_store(dh[par][3], hp + 3 * D_);
            atomicAdd(outputs + dob[par], dos[par]);
        }

        // prefetch next step's wx/z (clamped on last iter; harmless re-read)
        const int tn = (t + 1 < T_) ? t + 1 : t;
        float wx_n = wxall[(size_t)(tn * B_ + b) * D_ + dglob];
        float zv_n = z[(size_t)(tn * B_ + b) * D_ + dglob];

        floatx4 acc0 = {0.f, 0.f, 0.f, 0.f}, acc1 = acc0, acc2 = acc0, acc3 = acc0;
#pragma unroll
        for (int kt = 0; kt < 8; ++kt) {
            // A[m][k] = h_prev[slot m&3][k]; rows m>=4 broadcast rows 0-3
            acc0 = __builtin_amdgcn_mfma_f32_16x16x32_bf16(Af[kt], Bf[kt][0], acc0, 0, 0, 0);
            acc1 = __builtin_amdgcn_mfma_f32_16x16x32_bf16(Af[kt], Bf[kt][1], acc1, 0, 0, 0);
            acc2 = __builtin_amdgcn_mfma_f32_16x16x32_bf16(Af[kt], Bf[kt][2], acc2, 0, 0, 0);
            acc3 = __builtin_amdgcn_mfma_f32_16x16x32_bf16(Af[kt], Bf[kt][3], acc3, 0, 0, 0);
        }

        float sig  = __builtin_amdgcn_rcpf(1.0f + __expf(-zv));
        float silu = zv * sig;
        float osum = 0.0f;
#pragma unroll
        for (int r = 0; r < 4; ++r) {
            // C rows are replicated across quads (A rows m>=4 duplicate m&3), so
            // lane l already holds slot r / col l16 in ALL four accs at reg r;
            // it needs acc[quad] -> pure register select, no shuffles.
            float v01 = (quad & 1) ? acc1[r] : acc0[r];
            float v23 = (quad & 1) ? acc3[r] : acc2[r];
            float v   = (quad & 2) ? v23 : v01;
            float pre = v + wx;
            float hv  = tanh_fast(pre);
            hA[nxt][r][dglob] = f2bf(hv);     // next step's A operand
            dh[par][r] = hv;                  // deferred h_out store
            float cr = (r == 0) ? Cc0 : (r == 1) ? Cc1 : (r == 2) ? Cc2 : Cc3;
            osum = __builtin_fmaf(cr, hv, osum);
        }
        dhb[par] = ((size_t)(t + 1) * B_ + b) * (S_ * D_) + (size_t)s0 * D_ + dglob;
        dob[par] = (size_t)(t * B_ + b) * D_ + dglob;
        dos[par] = osum * silu;
        wx = wx_n; zv = zv_n;
        __syncthreads();   // ping-pong: single barrier per step
    }

    // tail: flush the last two steps
#pragma unroll
    for (int p = 0; p < 2; ++p) {
        float* hp = h_out + dhb[p];
        __builtin_nontemporal_store(dh[p][0], hp);
        __builtin_nontemporal_store(dh[p][1], hp + D_);
        __builtin_nontemporal_store(dh[p][2], hp + 2 * D_);
        __builtin_nontemporal_store(dh[p][3], hp + 3 * D_);
        atomicAdd(outputs + dob[p], dos[p]);
    }
}

extern "C" void kernel_launch(void* const* d_in, const int* in_sizes, int n_in,
                              void* d_out, int out_size, void* d_ws, size_t ws_size,
                              hipStream_t stream) {
    const float* x    = (const float*)d_in[0];
    const float* z    = (const float*)d_in[1];
    const float* h0   = (const float*)d_in[2];
    const float* W_x  = (const float*)d_in[3];
    const float* W_h  = (const float*)d_in[4];
    const float* bias = (const float*)d_in[5];
    const float* C    = (const float*)d_in[6];

    float* outputs = (float*)d_out;                     // [T*B*D]
    float* h_out   = outputs + (size_t)T_ * B_ * D_;    // [(T+1)*B*S*D]

    float* WxT   = (float*)d_ws;                        // D*D floats
    float* wxall = WxT + D_ * D_;                       // T*B*D floats

    hipMemsetAsync(outputs, 0, (size_t)T_ * B_ * D_ * sizeof(float), stream);
    k_transpose<<<64, 1024, 0, stream>>>(W_x, WxT);
    k_wxall<<<T_ * B_ / 16, 256, 0, stream>>>(x, WxT, bias, wxall);
    k_rec<<<B_ * S_ / 4, 256, 0, stream>>>(W_h, wxall, z, h0, C, outputs, h_out);
}

// Round 3
// 418.710 us; speedup vs baseline: 1.2184x; 1.1402x over previous
//
#include <hip/hip_runtime.h>
#include <hip/hip_bf16.h>

#define T_ 256
#define B_ 16
#define S_ 64
#define D_ 256

typedef __attribute__((ext_vector_type(8))) short short8;
typedef __attribute__((ext_vector_type(4))) float floatx4;

__device__ __forceinline__ short f2bf(float f) {
    union { float f; unsigned u; } uf; uf.f = f;
    unsigned r = uf.u + 0x7FFFu + ((uf.u >> 16) & 1u);  // RNE to bf16
    return (short)(r >> 16);
}

__device__ __forceinline__ float tanh_fast(float x) {
    // tanh(x) = 1 - 2/(1+exp(2x)); saturates correctly at +-inf
    float e = __expf(2.0f * x);
    float r = __builtin_amdgcn_rcpf(e + 1.0f);
    return __builtin_fmaf(-2.0f, r, 1.0f);
}

// ---------------- W_x transpose: WxT[k][d] = W_x[d][k] ----------------
__global__ void k_transpose(const float* __restrict__ in, float* __restrict__ out) {
    __shared__ float tile[32][33];
    int tx = threadIdx.x & 31, ty = threadIdx.x >> 5;
    int bx = blockIdx.x & 7, by = blockIdx.x >> 3;
    tile[ty][tx] = in[(by * 32 + ty) * D_ + bx * 32 + tx];
    __syncthreads();
    out[(bx * 32 + ty) * D_ + by * 32 + tx] = tile[tx][ty];
}

// -------- Wxall[t*B+b][d] = bias[d] + sum_k x[t,b,k] * WxT[k][d] --------
__global__ __launch_bounds__(256) void k_wxall(const float* __restrict__ x,
                                               const float* __restrict__ WxT,
                                               const float* __restrict__ bias,
                                               float* __restrict__ wxall) {
    __shared__ float xs[16][D_];
    const int tid = threadIdx.x;
    const int row0 = blockIdx.x * 16;
    for (int r = 0; r < 16; ++r)
        xs[r][tid] = x[(size_t)(row0 + r) * D_ + tid];
    __syncthreads();
    float acc[16];
    float bv = bias[tid];
#pragma unroll
    for (int r = 0; r < 16; ++r) acc[r] = bv;
    for (int k = 0; k < D_; ++k) {
        float wv = WxT[k * D_ + tid];
#pragma unroll
        for (int r = 0; r < 16; ++r) acc[r] = __builtin_fmaf(wv, xs[r][k], acc[r]);
    }
    for (int r = 0; r < 16; ++r)
        wxall[(size_t)(row0 + r) * D_ + tid] = acc[r];
}

// ---------------- main recurrence ----------------
// grid = 256 blocks: block -> (b = blk>>4, slots s0..s0+3, s0 = (blk&15)*4)
// block = 512 threads = 8 waves (2/SIMD); wave w owns n-slice [32w, 32w+32)
// Epilogue: lane l -> column d = 32w + (l&31); quad&1 = n-tile select,
// quad&2 = slot-pair select (r0 = quad&2) -> 2 tanh per thread.
__global__ __launch_bounds__(512, 1) void k_rec(
    const float* __restrict__ Wh,      // [D][D]
    const float* __restrict__ wxall,   // [T*B][D], bias folded in
    const float* __restrict__ z,       // [T*B][D]
    const float* __restrict__ h0,      // [B][S][D]
    const float* __restrict__ Cvec,    // [S]
    float* __restrict__ outputs,       // [T*B][D], pre-zeroed (atomic accum)
    float* __restrict__ h_out)         // [(T+1)*B][S][D]
{
    const int tid  = threadIdx.x;
    const int w    = tid >> 6;
    const int lane = tid & 63;
    const int l16  = lane & 15;
    const int quad = lane >> 4;
    const int b    = blockIdx.x >> 4;
    const int s0   = (blockIdx.x & 15) * 4;
    const int r0   = quad & 2;                 // slot-pair this thread finalizes
    const int d    = (w << 5) | (lane & 31);   // this thread's output column

    // ping-pong h buffer, bf16. row stride 272 shorts: b128 reads are 2-way
    // per bank (free, m136); b16 writes split quads across bank halves (free).
    __shared__ __align__(16) short hA[2][4][272];

    // init hA[0] from h0 and write h[0] = h0
    for (int i = tid; i < 4 * D_; i += 512) {
        int r = i >> 8, dd = i & 255;
        float v = h0[(size_t)(b * S_ + s0 + r) * D_ + dd];
        hA[0][r][dd] = f2bf(v);
        h_out[(size_t)(b * S_ + s0 + r) * D_ + dd] = v;
    }

    // Wh B-fragments: B[k][n] = Wh[n][k]; lane holds
    // B[k = kt*32 + quad*8 + j][n = 32w + nt*16 + l16]   (64 VGPRs total)
    short8 Bf[8][2];
#pragma unroll
    for (int nt = 0; nt < 2; ++nt) {
        const float* wr = Wh + (size_t)(w * 32 + nt * 16 + l16) * D_ + quad * 8;
#pragma unroll
        for (int kt = 0; kt < 8; ++kt) {
            const float* p = wr + kt * 32;
            float4 lo = *(const float4*)(p);
            float4 hi = *(const float4*)(p + 4);
            short8 v;
            v[0] = f2bf(lo.x); v[1] = f2bf(lo.y); v[2] = f2bf(lo.z); v[3] = f2bf(lo.w);
            v[4] = f2bf(hi.x); v[5] = f2bf(hi.y); v[6] = f2bf(hi.z); v[7] = f2bf(hi.w);
            Bf[kt][nt] = v;
        }
    }

    const float c0 = Cvec[s0 + r0], c1 = Cvec[s0 + r0 + 1];
    __syncthreads();

    float wx = wxall[(unsigned)b * D_ + d];   // t=0 row
    float zv = z[(unsigned)b * D_ + d];

    // 2-deep deferred global stores (parity = t&1), flushed at t+2 so the
    // pre-barrier vmcnt drain never waits on a fresh HBM store/atomic.
    float dh0_0, dh1_0, dos_0; unsigned dhb_0, dob_0;
    float dh0_1, dh1_1, dos_1; unsigned dhb_1, dob_1;

#define STEP(t, CUR, NXT)                                                      \
    {                                                                          \
        short8 Af[8];                                                          \
        _Pragma("unroll")                                                      \
        for (int kt = 0; kt < 8; ++kt)                                         \
            Af[kt] = *(const short8*)&hA[CUR][l16 & 3][kt * 32 + quad * 8];    \
        if ((t) >= 2) { /* flush step t-2 (same parity) */                     \
            float* hp = h_out + dhb_##CUR;                                     \
            __builtin_nontemporal_store(dh0_##CUR, hp);                        \
            __builtin_nontemporal_store(dh1_##CUR, hp + D_);                   \
            if (quad < 2) atomicAdd(outputs + dob_##CUR, dos_##CUR);           \
        }                                                                      \
        const int tn = ((t) + 1 < T_) ? (t) + 1 : (t);                         \
        float wx_n = wxall[(unsigned)(tn * B_ + b) * D_ + d];                  \
        float zv_n = z[(unsigned)(tn * B_ + b) * D_ + d];                      \
        floatx4 acc0 = {0.f, 0.f, 0.f, 0.f}, acc1 = acc0;                      \
        _Pragma("unroll")                                                      \
        for (int kt = 0; kt < 8; ++kt) {                                       \
            acc0 = __builtin_amdgcn_mfma_f32_16x16x32_bf16(Af[kt], Bf[kt][0], acc0, 0, 0, 0); \
            acc1 = __builtin_amdgcn_mfma_f32_16x16x32_bf16(Af[kt], Bf[kt][1], acc1, 0, 0, 0); \
        }                                                                      \
        /* C rows are quad-replicated (A rows m>=4 duplicate m&3):           */\
        /* lane needs acc[nt = quad&1] regs {r0, r0+1} -> pure selects.      */\
        float x0 = (quad & 2) ? acc0[2] : acc0[0];                             \
        float x1 = (quad & 2) ? acc0[3] : acc0[1];                             \
        float y0 = (quad & 2) ? acc1[2] : acc1[0];                             \
        float y1 = (quad & 2) ? acc1[3] : acc1[1];                             \
        float va = (quad & 1) ? y0 : x0;                                       \
        float vb = (quad & 1) ? y1 : x1;                                       \
        float hv0 = tanh_fast(va + wx);                                        \
        float hv1 = tanh_fast(vb + wx);                                        \
        short* wp = &hA[NXT][0][d] + r0 * 272;                                 \
        wp[0]   = f2bf(hv0);                                                   \
        wp[272] = f2bf(hv1);                                                   \
        float sig  = __builtin_amdgcn_rcpf(1.0f + __expf(-zv));                \
        float osum = __builtin_fmaf(c0, hv0, c1 * hv1);                        \
        osum += __shfl_xor(osum, 32, 64); /* combine slot-pairs for this d */  \
        dh0_##CUR = hv0; dh1_##CUR = hv1;                                      \
        dhb_##CUR = (unsigned)(((t) + 1) * B_ + b) * (S_ * D_) +               \
                    (unsigned)(s0 + r0) * D_ + d;                              \
        dob_##CUR = (unsigned)((t) * B_ + b) * D_ + d;                         \
        dos_##CUR = osum * (zv * sig);                                         \
        wx = wx_n; zv = zv_n;                                                  \
        __syncthreads();                                                       \
    }

    for (int t2 = 0; t2 < T_; t2 += 2) {
        STEP(t2, 0, 1)
        STEP(t2 + 1, 1, 0)
    }
#undef STEP

    // tail: flush the last two steps
    {
        float* hp = h_out + dhb_0;
        __builtin_nontemporal_store(dh0_0, hp);
        __builtin_nontemporal_store(dh1_0, hp + D_);
        if (quad < 2) atomicAdd(outputs + dob_0, dos_0);
        hp = h_out + dhb_1;
        __builtin_nontemporal_store(dh0_1, hp);
        __builtin_nontemporal_store(dh1_1, hp + D_);
        if (quad < 2) atomicAdd(outputs + dob_1, dos_1);
    }
}

extern "C" void kernel_launch(void* const* d_in, const int* in_sizes, int n_in,
                              void* d_out, int out_size, void* d_ws, size_t ws_size,
                              hipStream_t stream) {
    const float* x    = (const float*)d_in[0];
    const float* z    = (const float*)d_in[1];
    const float* h0   = (const float*)d_in[2];
    const float* W_x  = (const float*)d_in[3];
    const float* W_h  = (const float*)d_in[4];
    const float* bias = (const float*)d_in[5];
    const float* C    = (const float*)d_in[6];

    float* outputs = (float*)d_out;                     // [T*B*D]
    float* h_out   = outputs + (size_t)T_ * B_ * D_;    // [(T+1)*B*S*D]

    float* WxT   = (float*)d_ws;                        // D*D floats
    float* wxall = WxT + D_ * D_;                       // T*B*D floats

    hipMemsetAsync(outputs, 0, (size_t)T_ * B_ * D_ * sizeof(float), stream);
    k_transpose<<<64, 1024, 0, stream>>>(W_x, WxT);
    k_wxall<<<T_ * B_ / 16, 256, 0, stream>>>(x, WxT, bias, wxall);
    k_rec<<<B_ * S_ / 4, 512, 0, stream>>>(W_h, wxall, z, h0, C, outputs, h_out);
}

// Round 4
// 405.215 us; speedup vs baseline: 1.2589x; 1.0333x over previous
//
#include <hip/hip_runtime.h>
#include <hip/hip_bf16.h>

#define T_ 256
#define B_ 16
#define S_ 64
#define D_ 256

typedef __attribute__((ext_vector_type(4))) int int4v;

__device__ __forceinline__ float tanh_fast(float x) {
    // tanh(x) = 1 - 2/(1+exp(2x)); saturates correctly at +-inf
    float e = __expf(2.0f * x);
    float r = __builtin_amdgcn_rcpf(e + 1.0f);
    return __builtin_fmaf(-2.0f, r, 1.0f);
}

// ---------------- W_x transpose: WxT[k][d] = W_x[d][k] ----------------
__global__ void k_transpose(const float* __restrict__ in, float* __restrict__ out) {
    __shared__ float tile[32][33];
    int tx = threadIdx.x & 31, ty = threadIdx.x >> 5;
    int bx = blockIdx.x & 7, by = blockIdx.x >> 3;
    tile[ty][tx] = in[(by * 32 + ty) * D_ + bx * 32 + tx];
    __syncthreads();
    out[(bx * 32 + ty) * D_ + by * 32 + tx] = tile[tx][ty];
}

// -------- Wxall[t*B+b][d] = bias[d] + sum_k x[t,b,k] * WxT[k][d] --------
__global__ __launch_bounds__(256) void k_wxall(const float* __restrict__ x,
                                               const float* __restrict__ WxT,
                                               const float* __restrict__ bias,
                                               float* __restrict__ wxall) {
    __shared__ float xs[16][D_];
    const int tid = threadIdx.x;
    const int row0 = blockIdx.x * 16;
    for (int r = 0; r < 16; ++r)
        xs[r][tid] = x[(size_t)(row0 + r) * D_ + tid];
    __syncthreads();
    float acc[16];
    float bv = bias[tid];
#pragma unroll
    for (int r = 0; r < 16; ++r) acc[r] = bv;
    for (int k = 0; k < D_; ++k) {
        float wv = WxT[k * D_ + tid];
#pragma unroll
        for (int r = 0; r < 16; ++r) acc[r] = __builtin_fmaf(wv, xs[r][k], acc[r]);
    }
    for (int r = 0; r < 16; ++r)
        wxall[(size_t)(row0 + r) * D_ + tid] = acc[r];
}

// ---------------- main recurrence (i8 MFMA, K=64) ----------------
// grid = 256 blocks: block -> (b = blk>>4, slots s0..s0+3, s0 = (blk&15)*4)
// block = 512 threads = 8 waves (2/SIMD); wave w owns n-slice [32w, 32w+32)
// h feedback quantized to i8 (|h|<1 -> scale 127); Wh quantized i8 with a
// per-column scale (C-col = B-n = l16, so each lane owns its column's scale).
__global__ __launch_bounds__(512, 2) void k_rec(
    const float* __restrict__ Wh,      // [D][D] (n-major: Wh[n][k])
    const float* __restrict__ wxall,   // [T*B][D], bias folded in
    const float* __restrict__ z,       // [T*B][D]
    const float* __restrict__ h0,      // [B][S][D]
    const float* __restrict__ Cvec,    // [S]
    float* __restrict__ outputs,       // [T*B][D], pre-zeroed (atomic accum)
    float* __restrict__ h_out)         // [(T+1)*B][S][D]
{
    const int tid  = threadIdx.x;
    const int w    = tid >> 6;
    const int lane = tid & 63;
    const int l16  = lane & 15;
    const int quad = lane >> 4;
    const int b    = blockIdx.x >> 4;
    const int s0   = (blockIdx.x & 15) * 4;
    const int r0   = quad & 2;                 // slot-pair this thread finalizes
    const int d    = (w << 5) | (lane & 31);   // this thread's output column

    // ping-pong h buffer, i8. Row stride 288 B: b128 A-reads map each of the
    // 16 distinct (row,quad) chunks to start-banks {0,4,..,28}x2 = clean 2-way.
    __shared__ __align__(16) signed char hA8[2][4][288];

    // init hA8[0] from h0 and write h[0] = h0
    for (int i = tid; i < 4 * D_; i += 512) {
        int r = i >> 8, dd = i & 255;
        float v = h0[(size_t)(b * S_ + s0 + r) * D_ + dd];
        float vc = fminf(fmaxf(v, -1.0f), 1.0f);
        hA8[0][r][dd] = (signed char)__float2int_rn(vc * 127.0f);
        h_out[(size_t)(b * S_ + s0 + r) * D_ + dd] = v;
    }

    // ---- pass 1: per-column absmax of Wh for this lane's two columns ----
    // lane covers k = kt*64 + quad*16 + {0..15}, kt=0..3 (64 of 256 k); the
    // rest come from the other quads -> shfl_xor max-reduce over lane bits 4,5.
    float cmax[2];
#pragma unroll
    for (int nt = 0; nt < 2; ++nt) {
        const float* wr = Wh + (size_t)(w * 32 + nt * 16 + l16) * D_ + quad * 16;
        float cm = 1e-20f;
#pragma unroll
        for (int kt = 0; kt < 4; ++kt) {
            const float* p = wr + kt * 64;
#pragma unroll
            for (int j = 0; j < 16; j += 4) {
                float4 v = *(const float4*)(p + j);
                cm = fmaxf(cm, fmaxf(fmaxf(fabsf(v.x), fabsf(v.y)),
                                     fmaxf(fabsf(v.z), fabsf(v.w))));
            }
        }
        cm = fmaxf(cm, __shfl_xor(cm, 16, 64));
        cm = fmaxf(cm, __shfl_xor(cm, 32, 64));
        cmax[nt] = cm;
    }

    // ---- pass 2: quantize Wh -> i8 B-fragments (32 VGPRs total) ----
    // lane holds B[k = kt*64 + quad*16 + j][n = 32w + nt*16 + l16]
    int4v Bf[4][2];
#pragma unroll
    for (int nt = 0; nt < 2; ++nt) {
        const float rs = 127.0f / cmax[nt];
        const float* wr = Wh + (size_t)(w * 32 + nt * 16 + l16) * D_ + quad * 16;
#pragma unroll
        for (int kt = 0; kt < 4; ++kt) {
            const float* p = wr + kt * 64;
            int4v frag;
#pragma unroll
            for (int r = 0; r < 4; ++r) {
                float4 v = *(const float4*)(p + r * 4);
                int q0 = __float2int_rn(v.x * rs) & 255;
                int q1 = __float2int_rn(v.y * rs) & 255;
                int q2 = __float2int_rn(v.z * rs) & 255;
                int q3 = __float2int_rn(v.w * rs) & 255;
                frag[r] = q0 | (q1 << 8) | (q2 << 16) | (q3 << 24);
            }
            Bf[kt][nt] = frag;
        }
    }

    // this thread's output-column dequant scale: col d -> nt = quad&1
    const float dscale = ((quad & 1) ? cmax[1] : cmax[0]) * (1.0f / 16129.0f);

    const float c0 = Cvec[s0 + r0], c1 = Cvec[s0 + r0 + 1];
    __syncthreads();

    float wx = wxall[(unsigned)b * D_ + d];   // t=0 row
    float zv = z[(unsigned)b * D_ + d];

    // 2-deep deferred global stores (parity = t&1), flushed at t+2 so the
    // pre-barrier vmcnt drain never waits on a fresh HBM store/atomic.
    float dh0_0, dh1_0, dos_0; unsigned dhb_0, dob_0;
    float dh0_1, dh1_1, dos_1; unsigned dhb_1, dob_1;

#define STEP(t, CUR, NXT)                                                      \
    {                                                                          \
        int4v Af[4];                                                           \
        _Pragma("unroll")                                                      \
        for (int kt = 0; kt < 4; ++kt)                                         \
            Af[kt] = *(const int4v*)&hA8[CUR][l16 & 3][kt * 64 + quad * 16];   \
        if ((t) >= 2) { /* flush step t-2 (same parity) */                     \
            float* hp = h_out + dhb_##CUR;                                     \
            __builtin_nontemporal_store(dh0_##CUR, hp);                        \
            __builtin_nontemporal_store(dh1_##CUR, hp + D_);                   \
            if (quad < 2) atomicAdd(outputs + dob_##CUR, dos_##CUR);           \
        }                                                                      \
        const int tn = ((t) + 1 < T_) ? (t) + 1 : (t);                         \
        float wx_n = wxall[(unsigned)(tn * B_ + b) * D_ + d];                  \
        float zv_n = z[(unsigned)(tn * B_ + b) * D_ + d];                      \
        int4v acc0 = {0, 0, 0, 0}, acc1 = acc0;                                \
        _Pragma("unroll")                                                      \
        for (int kt = 0; kt < 4; ++kt) {                                       \
            acc0 = __builtin_amdgcn_mfma_i32_16x16x64_i8(Af[kt], Bf[kt][0], acc0, 0, 0, 0); \
            acc1 = __builtin_amdgcn_mfma_i32_16x16x64_i8(Af[kt], Bf[kt][1], acc1, 0, 0, 0); \
        }                                                                      \
        /* C rows quad-replicated (A rows m>=4 duplicate m&3): reg r = slot r */\
        int ia = (quad & 2) ? acc0[2] : acc0[0];                               \
        int ib = (quad & 2) ? acc0[3] : acc0[1];                               \
        int ja = (quad & 2) ? acc1[2] : acc1[0];                               \
        int jb = (quad & 2) ? acc1[3] : acc1[1];                               \
        int sa = (quad & 1) ? ja : ia;                                         \
        int sb = (quad & 1) ? jb : ib;                                         \
        float hv0 = tanh_fast(__builtin_fmaf((float)sa, dscale, wx));          \
        float hv1 = tanh_fast(__builtin_fmaf((float)sb, dscale, wx));          \
        hA8[NXT][r0][d]     = (signed char)__float2int_rn(hv0 * 127.0f);       \
        hA8[NXT][r0 + 1][d] = (signed char)__float2int_rn(hv1 * 127.0f);       \
        float sig  = __builtin_amdgcn_rcpf(1.0f + __expf(-zv));                \
        float osum = __builtin_fmaf(c0, hv0, c1 * hv1);                        \
        osum += __shfl_xor(osum, 32, 64); /* combine slot-pairs for this d */  \
        dh0_##CUR = hv0; dh1_##CUR = hv1;                                      \
        dhb_##CUR = (unsigned)(((t) + 1) * B_ + b) * (S_ * D_) +               \
                    (unsigned)(s0 + r0) * D_ + d;                              \
        dob_##CUR = (unsigned)((t) * B_ + b) * D_ + d;                         \
        dos_##CUR = osum * (zv * sig);                                         \
        wx = wx_n; zv = zv_n;                                                  \
        __syncthreads();                                                       \
    }

    for (int t2 = 0; t2 < T_; t2 += 2) {
        STEP(t2, 0, 1)
        STEP(t2 + 1, 1, 0)
    }
#undef STEP

    // tail: flush the last two steps
    {
        float* hp = h_out + dhb_0;
        __builtin_nontemporal_store(dh0_0, hp);
        __builtin_nontemporal_store(dh1_0, hp + D_);
        if (quad < 2) atomicAdd(outputs + dob_0, dos_0);
        hp = h_out + dhb_1;
        __builtin_nontemporal_store(dh0_1, hp);
        __builtin_nontemporal_store(dh1_1, hp + D_);
        if (quad < 2) atomicAdd(outputs + dob_1, dos_1);
    }
}

extern "C" void kernel_launch(void* const* d_in, const int* in_sizes, int n_in,
                              void* d_out, int out_size, void* d_ws, size_t ws_size,
                              hipStream_t stream) {
    const float* x    = (const float*)d_in[0];
    const float* z    = (const float*)d_in[1];
    const float* h0   = (const float*)d_in[2];
    const float* W_x  = (const float*)d_in[3];
    const float* W_h  = (const float*)d_in[4];
    const float* bias = (const float*)d_in[5];
    const float* C    = (const float*)d_in[6];

    float* outputs = (float*)d_out;                     // [T*B*D]
    float* h_out   = outputs + (size_t)T_ * B_ * D_;    // [(T+1)*B*S*D]

    float* WxT   = (float*)d_ws;                        // D*D floats
    float* wxall = WxT + D_ * D_;                       // T*B*D floats

    hipMemsetAsync(outputs, 0, (size_t)T_ * B_ * D_ * sizeof(float), stream);
    k_transpose<<<64, 1024, 0, stream>>>(W_x, WxT);
    k_wxall<<<T_ * B_ / 16, 256, 0, stream>>>(x, WxT, bias, wxall);
    k_rec<<<B_ * S_ / 4, 512, 0, stream>>>(W_h, wxall, z, h0, C, outputs, h_out);
}